// Round 18
// baseline (448.561 us; speedup 1.0000x reference)
//
#include <hip/hip_runtime.h>
#include <hip/hip_fp16.h>
#include <hip/hip_bf16.h>
#include <cstdint>
#include <cstddef>

#define D_HID 1024
#define MEM_M 20000
#define NBATCH 4
#define BL 32
#define NROWS 512
#define BK 32
#define LDT 40    // padded LDS row stride in ushorts (80B, 16B-aligned rows)
#define PV_NC 8   // K-chunks per bank in mfma_pv (part = 16*2MB = 33.5MB)

typedef __attribute__((ext_vector_type(8))) short short8;
typedef __attribute__((ext_vector_type(4))) float f32x4;
typedef __attribute__((ext_vector_type(16))) float f32x16;
typedef __attribute__((ext_vector_type(4))) unsigned short us4;

__device__ inline ushort f2bf(float f) {
    __hip_bfloat16 b = __float2bfloat16(f);
    return *reinterpret_cast<ushort*>(&b);
}
__device__ inline float h2f(ushort u) {
    __half h; *reinterpret_cast<ushort*>(&h) = u; return __half2float(h);
}
__device__ inline float bf2f(ushort u) {
    unsigned int bits = (unsigned int)u << 16;
    float f; __builtin_memcpy(&f, &bits, 4); return f;
}

// Barrier without the compiler's vmcnt(0) drain (LDS ordering only).
__device__ __forceinline__ void block_sync_lds() {
    asm volatile("s_waitcnt lgkmcnt(0)" ::: "memory");
    __builtin_amdgcn_s_barrier();
}

// ---------------------------------------------------------------------------
// Skinny GEMM (M<=32) split-K partials, shared body.
// ---------------------------------------------------------------------------
struct SkDesc  { const float* A; const float* B; int K; int M; };
struct SkDescs { SkDesc d[5]; };
struct RdDesc  { const float* bias; float* dst; int M; int ldc; float alpha; };
struct RdDescs { RdDesc d[5]; };

__device__ __forceinline__ void skinny_body(const SkDesc dd, float* __restrict__ part,
                                            int gk, int k0, int n0, int tid)
{
    __shared__ float As[32][132];
    __shared__ float Bs[64][129];
    const int K = dd.K, M = dd.M;
    {
        const int r = tid >> 3, cbl = (tid & 7) * 16;
        if (r < M) {
            const float* src = dd.A + (size_t)r * K + k0 + cbl;
            #pragma unroll
            for (int i = 0; i < 4; ++i) {
                const float4 v = *(const float4*)(src + i * 4);
                As[r][cbl + i * 4 + 0] = v.x; As[r][cbl + i * 4 + 1] = v.y;
                As[r][cbl + i * 4 + 2] = v.z; As[r][cbl + i * 4 + 3] = v.w;
            }
        } else {
            #pragma unroll
            for (int i = 0; i < 16; ++i) As[r][cbl + i] = 0.f;
        }
    }
    {
        const int r = tid >> 2, cbl = (tid & 3) * 32;
        const float* src = dd.B + (size_t)(n0 + r) * K + k0 + cbl;
        #pragma unroll
        for (int i = 0; i < 8; ++i) {
            const float4 v = *(const float4*)(src + i * 4);
            Bs[r][cbl + i * 4 + 0] = v.x; Bs[r][cbl + i * 4 + 1] = v.y;
            Bs[r][cbl + i * 4 + 2] = v.z; Bs[r][cbl + i * 4 + 3] = v.w;
        }
    }
    __syncthreads();
    const int n = tid & 63, mg = tid >> 6;
    float acc[8];
    #pragma unroll
    for (int i = 0; i < 8; ++i) acc[i] = 0.f;
    #pragma unroll 4
    for (int k = 0; k < 128; k += 4) {
        const float b0 = Bs[n][k + 0], b1 = Bs[n][k + 1];
        const float b2 = Bs[n][k + 2], b3 = Bs[n][k + 3];
        #pragma unroll
        for (int i = 0; i < 8; ++i) {
            const float4 a = *(const float4*)&As[mg * 8 + i][k];
            acc[i] = fmaf(a.x, b0, fmaf(a.y, b1, fmaf(a.z, b2, fmaf(a.w, b3, acc[i]))));
        }
    }
    #pragma unroll
    for (int i = 0; i < 8; ++i)
        part[((size_t)gk * 32 + mg * 8 + i) * 1024 + n0 + n] = acc[i];
}

__global__ __launch_bounds__(256)
void k_skinny(SkDescs ds, float* __restrict__ part)
{
    skinny_body(ds.d[blockIdx.z], part,
                blockIdx.z * gridDim.y + blockIdx.y,
                blockIdx.y * 128, blockIdx.x * 64, threadIdx.x);
}

// ---------------------------------------------------------------------------
// Fat head: skinny s1 (blocks [0,640)) || row-based cvt ek,sk -> bf16 kvb
// with FUSED write-path dots swr[b][r] = data[b]·ek[r] (fp32) ([640,2048)).
// ---------------------------------------------------------------------------
__global__ __launch_bounds__(256)
void k_head(SkDescs ds, float* __restrict__ part,
            const float* __restrict__ ek, const float* __restrict__ sk,
            ushort* __restrict__ kvb,
            const float* __restrict__ data, __half* __restrict__ swr)
{
    const int bx = blockIdx.x;
    const int tid = threadIdx.x;
    if (bx < 640) {
        const int g = bx >> 7;
        const int rem = bx & 127;
        const int kc = rem >> 4;
        const int n0 = (rem & 15) * 64;
        skinny_body(ds.d[g], part, g * 8 + kc, kc * 128, n0, tid);
    } else {
        const int lane = tid & 63;
        const int wv0 = (bx - 640) * 4 + (tid >> 6);   // wave id in [0,5632)
        const int c16 = lane * 16;
        float dreg[NBATCH][16];
        #pragma unroll
        for (int b = 0; b < NBATCH; ++b)
            #pragma unroll
            for (int j = 0; j < 16; j += 4)
                *(float4*)&dreg[b][j] = *(const float4*)(data + b * D_HID + c16 + j);
        for (int r = wv0; r < 2 * MEM_M; r += 5632) {
            const bool eb = (r < MEM_M);
            const float* src = eb ? (ek + (size_t)r * D_HID + c16)
                                  : (sk + (size_t)(r - MEM_M) * D_HID + c16);
            float v[16];
            #pragma unroll
            for (int j = 0; j < 16; j += 4)
                *(float4*)&v[j] = *(const float4*)(src + j);
            alignas(16) ushort o[16];
            #pragma unroll
            for (int j = 0; j < 16; ++j) o[j] = f2bf(v[j]);
            ushort* dst = kvb + (size_t)r * D_HID + c16;
            *(short8*)dst       = *(const short8*)&o[0];
            *(short8*)(dst + 8) = *(const short8*)&o[8];
            if (eb) {
                float dp[NBATCH];
                #pragma unroll
                for (int b = 0; b < NBATCH; ++b) {
                    float s = 0.f;
                    #pragma unroll
                    for (int j = 0; j < 16; ++j) s = fmaf(dreg[b][j], v[j], s);
                    dp[b] = s;
                }
                #pragma unroll
                for (int b = 0; b < NBATCH; ++b)
                    #pragma unroll
                    for (int off = 32; off > 0; off >>= 1)
                        dp[b] += __shfl_down(dp[b], off);
                if (lane == 0) {
                    #pragma unroll
                    for (int b = 0; b < NBATCH; ++b)
                        swr[(size_t)b * MEM_M + r] = __float2half(dp[b]);
                }
            }
        }
    }
}

__global__ __launch_bounds__(256)
void k_skred(RdDescs ds, const float* __restrict__ part, int nkc)
{
    const int g = blockIdx.y;
    const int m = blockIdx.x;
    const RdDesc dd = ds.d[g];
    if (m >= dd.M) return;
    const int c = threadIdx.x * 4;
    float4 s = make_float4(0.f, 0.f, 0.f, 0.f);
    for (int kc = 0; kc < nkc; ++kc) {
        const float4 v = *(const float4*)&part[((size_t)(g * nkc + kc) * 32 + m) * 1024 + c];
        s.x += v.x; s.y += v.y; s.z += v.z; s.w += v.w;
    }
    const float4 b = *(const float4*)(dd.bias + c);
    float4 o;
    o.x = (s.x + b.x) * dd.alpha; o.y = (s.y + b.y) * dd.alpha;
    o.z = (s.z + b.z) * dd.alpha; o.w = (s.w + b.w) * dd.alpha;
    *(float4*)(dd.dst + (size_t)m * dd.ldc + c) = o;
}

// ---------------------------------------------------------------------------
// MFMA bf16 scores GEMM, both banks 512 rows, (8,157) XCD-chunk swizzle,
// prefetch-2 LDS pipeline, 32x32x16 MFMA. Epilogue writes P = bf16(exp(S+c0)).
// ---------------------------------------------------------------------------
__global__ __launch_bounds__(256)
void mfma_scores(const ushort* __restrict__ A_e, const ushort* __restrict__ ekb,
                 const ushort* __restrict__ A_s, const ushort* __restrict__ skb,
                 ushort* __restrict__ P_e, ushort* __restrict__ P_s,
                 const float* __restrict__ c0_e, const float* __restrict__ c0_s)
{
    __shared__ ushort As[2][128][LDT];
    __shared__ ushort Bs[2][128][LDT];
    const int tid = threadIdx.x;
    // flatten (8,157); chunk = 157 per XCD, bijective
    const int i = blockIdx.x + 8 * blockIdx.y;
    const int xcd = i & 7, idx = i >> 3;
    const int wg = xcd * 157 + idx;
    const int mi = wg & 7, nbk = wg >> 3;
    const int bank = (mi >= 4);
    const int m0 = (bank ? (mi - 4) : mi) * 128;
    const int n0 = nbk * 128;
    const ushort* __restrict__ A = bank ? A_s : A_e;
    const ushort* __restrict__ B = bank ? skb : ekb;
    ushort* __restrict__ P = bank ? P_s : P_e;
    const float* __restrict__ c0 = bank ? c0_s : c0_e;

    const int wid = tid >> 6, lane = tid & 63;
    const int wr = (wid >> 1) * 64, wc = (wid & 1) * 64;
    const int l31 = lane & 31, l2 = lane >> 5;

    const int srow = tid >> 1;
    const int ac = (tid & 1) * 16;
    int gbrow = n0 + srow; if (gbrow > MEM_M - 1) gbrow = MEM_M - 1;
    const ushort* Ap = A + (size_t)(m0 + srow) * 1024 + ac;
    const ushort* Bp = B + (size_t)gbrow * 1024 + ac;

    f32x16 acc[2][2];
    #pragma unroll
    for (int fm = 0; fm < 2; ++fm)
        #pragma unroll
        for (int fn = 0; fn < 2; ++fn)
            #pragma unroll
            for (int r = 0; r < 16; ++r) acc[fm][fn][r] = 0.f;

    auto MF = [&](int bu) {
        short8 a[2][2], b[2][2];
        #pragma unroll
        for (int f = 0; f < 2; ++f)
            #pragma unroll
            for (int kh = 0; kh < 2; ++kh) {
                a[f][kh] = *(const short8*)&As[bu][wr + f * 32 + l31][kh * 16 + l2 * 8];
                b[f][kh] = *(const short8*)&Bs[bu][wc + f * 32 + l31][kh * 16 + l2 * 8];
            }
        #pragma unroll
        for (int fm = 0; fm < 2; ++fm)
            #pragma unroll
            for (int fn = 0; fn < 2; ++fn)
                #pragma unroll
                for (int kh = 0; kh < 2; ++kh)
                    acc[fm][fn] = __builtin_amdgcn_mfma_f32_32x32x16_bf16(
                        a[fm][kh], b[fn][kh], acc[fm][fn], 0, 0, 0);
    };

    short8 a00, a01, b00, b01;   // prefetch set 0 (even tiles)
    short8 a10, a11, b10, b11;   // prefetch set 1 (odd tiles)

#define SC_LOAD0(KT) { a00 = *(const short8*)(Ap + (KT)); a01 = *(const short8*)(Ap + (KT) + 8); \
                       b00 = *(const short8*)(Bp + (KT)); b01 = *(const short8*)(Bp + (KT) + 8); }
#define SC_LOAD1(KT) { a10 = *(const short8*)(Ap + (KT)); a11 = *(const short8*)(Ap + (KT) + 8); \
                       b10 = *(const short8*)(Bp + (KT)); b11 = *(const short8*)(Bp + (KT) + 8); }
#define SC_STORE0(BU) { *(short8*)&As[BU][srow][ac] = a00; *(short8*)&As[BU][srow][ac + 8] = a01; \
                        *(short8*)&Bs[BU][srow][ac] = b00; *(short8*)&Bs[BU][srow][ac + 8] = b01; }
#define SC_STORE1(BU) { *(short8*)&As[BU][srow][ac] = a10; *(short8*)&As[BU][srow][ac + 8] = a11; \
                        *(short8*)&Bs[BU][srow][ac] = b10; *(short8*)&Bs[BU][srow][ac + 8] = b11; }

    SC_LOAD0(0);
    SC_LOAD1(32);
    SC_STORE0(0);
    block_sync_lds();
    for (int it = 0; it < 16; ++it) {
        const int kt = it * 64;
        if (it < 15) SC_LOAD0(kt + 64);
        MF(0);
        SC_STORE1(1);
        block_sync_lds();
        if (it < 15) SC_LOAD1(kt + 96);
        MF(1);
        if (it < 15) SC_STORE0(0);
        block_sync_lds();
    }
#undef SC_LOAD0
#undef SC_LOAD1
#undef SC_STORE0
#undef SC_STORE1

    #pragma unroll
    for (int fm = 0; fm < 2; ++fm) {
        #pragma unroll
        for (int fn = 0; fn < 2; ++fn) {
            #pragma unroll
            for (int r = 0; r < 16; ++r) {
                const int row = m0 + wr + fm * 32 + (r & 3) + 8 * (r >> 2) + 4 * l2;
                const int col = n0 + wc + fn * 32 + l31;
                if (col < MEM_M)
                    P[(size_t)row * MEM_M + col] = f2bf(__expf(acc[fm][fn][r] + c0[row]));
            }
        }
    }
}

// ---------------------------------------------------------------------------
// MFMA bf16 PV GEMM with FUSED row-sum of P: nI==0 blocks accumulate lsum
// from the MFMA A-fragments (already in registers) and atomicAdd per row
// per k-chunk (8192 atomics total). lrow must be pre-zeroed (k_T).
// ---------------------------------------------------------------------------
__global__ __launch_bounds__(256)
void mfma_pv(const ushort* __restrict__ P_e, const ushort* __restrict__ P_s,
             const float* __restrict__ ev, const float* __restrict__ sv,
             float* __restrict__ part, float* __restrict__ lrow)
{
    __shared__ ushort As[2][128][LDT];
    __shared__ ushort Bs[2][128][LDT];
    const int tid = threadIdx.x;
    // chunked XCD swizzle (n fastest, then m, then z)
    const int bid = blockIdx.x + 8 * (blockIdx.y + 4 * blockIdx.z);
    const int wgs = (bid & 7) * 64 + (bid >> 3);
    const int nI = wgs & 7, mI = (wgs >> 3) & 3;
    const int z = wgs >> 5;                 // [0,16)
    const int bank = z >> 3, c = z & 7;
    const ushort* __restrict__ P = bank ? P_s : P_e;
    const float* __restrict__ V = bank ? sv : ev;
    const int m0 = mI * 128, n0 = nI * 128;
    const int ks0 = (c * 625) / PV_NC, ks1 = ((c + 1) * 625) / PV_NC;
    const int wid = tid >> 6, lane = tid & 63;
    const int wr = (wid >> 1) * 64, wc = (wid & 1) * 64;
    const int l31 = lane & 31, l2 = lane >> 5;
    const int kb = (tid & 7) * 4, nb2 = (tid >> 3) * 4;
    const int srow = tid >> 1, ac = (tid & 1) * 16;
    const ushort* Pp = P + (size_t)(m0 + srow) * MEM_M + ac;
    const bool doSum = (nI == 0) && !(wid & 1);   // wave-uniform
    float rsum0 = 0.f, rsum1 = 0.f;               // rows wr+l31, wr+32+l31

    f32x16 acc[2][2];
    #pragma unroll
    for (int fm = 0; fm < 2; ++fm)
        #pragma unroll
        for (int fn = 0; fn < 2; ++fn)
            #pragma unroll
            for (int r = 0; r < 16; ++r) acc[fm][fn][r] = 0.f;

    auto MF = [&](int bu) {
        short8 a[2][2], b[2][2];
        #pragma unroll
        for (int f = 0; f < 2; ++f)
            #pragma unroll
            for (int kh = 0; kh < 2; ++kh) {
                a[f][kh] = *(const short8*)&As[bu][wr + f * 32 + l31][kh * 16 + l2 * 8];
                b[f][kh] = *(const short8*)&Bs[bu][wc + f * 32 + l31][kh * 16 + l2 * 8];
            }
        if (doSum) {
            #pragma unroll
            for (int kh = 0; kh < 2; ++kh)
                #pragma unroll
                for (int j = 0; j < 8; ++j) {
                    rsum0 += bf2f((ushort)a[0][kh][j]);
                    rsum1 += bf2f((ushort)a[1][kh][j]);
                }
        }
        #pragma unroll
        for (int fm = 0; fm < 2; ++fm)
            #pragma unroll
            for (int fn = 0; fn < 2; ++fn)
                #pragma unroll
                for (int kh = 0; kh < 2; ++kh)
                    acc[fm][fn] = __builtin_amdgcn_mfma_f32_32x32x16_bf16(
                        a[fm][kh], b[fn][kh], acc[fm][fn], 0, 0, 0);
    };

    short8 pa00, pa01, pa10, pa11;
    float4 q00, q01, q02, q03, q10, q11, q12, q13;

#define PV_LOAD0(T) { const int kt = (T) * 32; \
    pa00 = *(const short8*)(Pp + kt); pa01 = *(const short8*)(Pp + kt + 8); \
    q00 = *(const float4*)(V + (size_t)(kt + kb + 0) * 1024 + n0 + nb2); \
    q01 = *(const float4*)(V + (size_t)(kt + kb + 1) * 1024 + n0 + nb2); \
    q02 = *(const float4*)(V + (size_t)(kt + kb + 2) * 1024 + n0 + nb2); \
    q03 = *(const float4*)(V + (size_t)(kt + kb + 3) * 1024 + n0 + nb2); }
#define PV_LOAD1(T) { const int kt = (T) * 32; \
    pa10 = *(const short8*)(Pp + kt); pa11 = *(const short8*)(Pp + kt + 8); \
    q10 = *(const float4*)(V + (size_t)(kt + kb + 0) * 1024 + n0 + nb2); \
    q11 = *(const float4*)(V + (size_t)(kt + kb + 1) * 1024 + n0 + nb2); \
    q12 = *(const float4*)(V + (size_t)(kt + kb + 2) * 1024 + n0 + nb2); \
    q13 = *(const float4*)(V + (size_t)(kt + kb + 3) * 1024 + n0 + nb2); }
#define PV_STORE0(BU) { \
    *(short8*)&As[BU][srow][ac] = pa00; *(short8*)&As[BU][srow][ac + 8] = pa01; \
    us4 w; \
    w.x = f2bf(q00.x); w.y = f2bf(q01.x); w.z = f2bf(q02.x); w.w = f2bf(q03.x); \
    *(us4*)&Bs[BU][nb2 + 0][kb] = w; \
    w.x = f2bf(q00.y); w.y = f2bf(q01.y); w.z = f2bf(q02.y); w.w = f2bf(q03.y); \
    *(us4*)&Bs[BU][nb2 + 1][kb] = w; \
    w.x = f2bf(q00.z); w.y = f2bf(q01.z); w.z = f2bf(q02.z); w.w = f2bf(q03.z); \
    *(us4*)&Bs[BU][nb2 + 2][kb] = w; \
    w.x = f2bf(q00.w); w.y = f2bf(q01.w); w.z = f2bf(q02.w); w.w = f2bf(q03.w); \
    *(us4*)&Bs[BU][nb2 + 3][kb] = w; }
#define PV_STORE1(BU) { \
    *(short8*)&As[BU][srow][ac] = pa10; *(short8*)&As[BU][srow][ac + 8] = pa11; \
    us4 w; \
    w.x = f2bf(q10.x); w.y = f2bf(q11.x); w.z = f2bf(q12.x); w.w = f2bf(q13.x); \
    *(us4*)&Bs[BU][nb2 + 0][kb] = w; \
    w.x = f2bf(q10.y); w.y = f2bf(q11.y); w.z = f2bf(q12.y); w.w = f2bf(q13.y); \
    *(us4*)&Bs[BU][nb2 + 1][kb] = w; \
    w.x = f2bf(q10.z); w.y = f2bf(q11.z); w.z = f2bf(q12.z); w.w = f2bf(q13.z); \
    *(us4*)&Bs[BU][nb2 + 2][kb] = w; \
    w.x = f2bf(q10.w); w.y = f2bf(q11.w); w.z = f2bf(q12.w); w.w = f2bf(q13.w); \
    *(us4*)&Bs[BU][nb2 + 3][kb] = w; }

    PV_LOAD0(ks0);
    if (ks0 + 1 < ks1) PV_LOAD1(ks0 + 1);
    PV_STORE0(0);
    block_sync_lds();
    for (int t = ks0; t < ks1; t += 2) {
        if (t + 2 < ks1) PV_LOAD0(t + 2);
        MF(0);
        if (t + 1 < ks1) PV_STORE1(1);
        block_sync_lds();
        if (t + 1 < ks1) {
            if (t + 3 < ks1) PV_LOAD1(t + 3);
            MF(1);
            if (t + 2 < ks1) PV_STORE0(0);
            block_sync_lds();
        }
    }
#undef PV_LOAD0
#undef PV_LOAD1
#undef PV_STORE0
#undef PV_STORE1

    if (nI == 0 && !(wid & 1)) {
        rsum0 += __shfl_down(rsum0, 32);
        rsum1 += __shfl_down(rsum1, 32);
        if (lane < 32) {
            atomicAdd(&lrow[bank * NROWS + m0 + wr + lane], rsum0);
            atomicAdd(&lrow[bank * NROWS + m0 + wr + 32 + lane], rsum1);
        }
    }

    float* __restrict__ po = part + (size_t)z * NROWS * 1024;
    #pragma unroll
    for (int fm = 0; fm < 2; ++fm)
        #pragma unroll
        for (int fn = 0; fn < 2; ++fn)
            #pragma unroll
            for (int r = 0; r < 16; ++r) {
                const int row = m0 + wr + fm * 32 + (r & 3) + 8 * (r >> 2) + 4 * l2;
                const int col = n0 + wc + fn * 32 + l31;
                po[(size_t)row * 1024 + col] = acc[fm][fn][r];
            }
}

// ---------------------------------------------------------------------------
// T rows (folded K-projection), bf16 output; fused dmean prep + lrow zero.
// ---------------------------------------------------------------------------
__global__ __launch_bounds__(256)
void k_T(const float* __restrict__ qp,
         const float* __restrict__ Wi_e, const float* __restrict__ bi_e,
         const float* __restrict__ Wi_s, const float* __restrict__ bi_s,
         ushort* __restrict__ A_e, float* __restrict__ c0_e,
         ushort* __restrict__ A_s, float* __restrict__ c0_s,
         const float* __restrict__ data, float* __restrict__ dmean,
         float* __restrict__ lrow)
{
    const int bq = blockIdx.x;
    const int tid = threadIdx.x;
    if (bq >= 128) {
        for (int t = tid; t < D_HID; t += 256) {
            float s = 0.f;
            #pragma unroll
            for (int b = 0; b < NBATCH; ++b) s += data[b * D_HID + t];
            dmean[t] = 0.25f * s;
        }
        for (int t = tid; t < 2 * NROWS; t += 256) lrow[t] = 0.f;
        return;
    }
    const int bank = bq >> 6;
    const int h = (bq >> 2) & 15;
    const int q4 = bq & 3;
    const float* qpB = qp + (size_t)bank * BL * D_HID;
    const float* Wk = (bank ? Wi_s : Wi_e) + (size_t)D_HID * D_HID;
    const float* bk = (bank ? bi_s : bi_e) + D_HID;
    ushort* T  = bank ? A_s : A_e;
    float* c0 = bank ? c0_s : c0_e;

    __shared__ float qs[32][64];
    for (int i = tid; i < 32 * 64; i += 256) {
        const int r = i >> 6, j = i & 63;
        qs[r][j] = qpB[(size_t)r * D_HID + h * 64 + j];
    }
    __syncthreads();
    const int e = q4 * 256 + tid;
    float acc[32];
    #pragma unroll
    for (int r = 0; r < 32; ++r) acc[r] = 0.f;
    for (int j = 0; j < 64; ++j) {
        const float w = Wk[(size_t)(h * 64 + j) * D_HID + e];
        #pragma unroll
        for (int r = 0; r < 32; ++r) acc[r] = fmaf(qs[r][j], w, acc[r]);
    }
    #pragma unroll
    for (int r = 0; r < 32; ++r) T[(size_t)(r * 16 + h) * 1024 + e] = f2bf(acc[r]);
    if (q4 == 0 && tid < 32) {
        float s = 0.f;
        for (int j = 0; j < 64; ++j) s += qs[tid][j] * bk[h * 64 + j];
        c0[tid * 16 + h] = s;
    }
}

// ---------------------------------------------------------------------------
// Stats (m,l) for the 4 write-path rows only (large-magnitude scores in swr).
// ---------------------------------------------------------------------------
__global__ __launch_bounds__(256)
void k_wstat(const __half* __restrict__ swr,
             float* __restrict__ mrow, float* __restrict__ lrow)
{
    const int b = blockIdx.x;                 // 0..3
    const ushort* p = (const ushort*)swr + (size_t)b * MEM_M;
    __shared__ float red_m[256];
    __shared__ float red_l[256];
    const int tid = threadIdx.x;
    float m = -3.0e38f, l = 0.f;
    for (int c = tid; c < MEM_M / 8; c += 256) {
        alignas(16) ushort t[8];
        *(short8*)t = *(const short8*)(p + c * 8);
        float v[8];
        #pragma unroll
        for (int j = 0; j < 8; ++j) v[j] = h2f(t[j]);
        float cm = v[0];
        #pragma unroll
        for (int j = 1; j < 8; ++j) cm = fmaxf(cm, v[j]);
        const float nm = fmaxf(m, cm);
        float s = 0.f;
        #pragma unroll
        for (int j = 0; j < 8; ++j) s += __expf(v[j] - nm);
        l = l * __expf(m - nm) + s;
        m = nm;
    }
    red_m[tid] = m; red_l[tid] = l; __syncthreads();
    for (int s = 128; s > 0; s >>= 1) {
        if (tid < s) {
            const float m2 = fmaxf(red_m[tid], red_m[tid + s]);
            red_l[tid] = red_l[tid] * __expf(red_m[tid] - m2)
                       + red_l[tid + s] * __expf(red_m[tid + s] - m2);
            red_m[tid] = m2;
        }
        __syncthreads();
    }
    if (tid == 0) { mrow[2 * NROWS + b] = red_m[0]; lrow[2 * NROWS + b] = red_l[0]; }
}

// u[k] and new_eu[k] from the 4 write-path fp16 rows in swr.
__global__ __launch_bounds__(256)
void k_uk(const __half* __restrict__ swr,
          const float* __restrict__ mrow, const float* __restrict__ lrow,
          const float* __restrict__ eu,
          float* __restrict__ u, float* __restrict__ out_eu)
{
    const int k = blockIdx.x * 256 + threadIdx.x;
    if (k >= MEM_M) return;
    float sp = 0.f;
    #pragma unroll
    for (int b = 0; b < NBATCH; ++b) {
        const int row = 2 * NROWS + b;
        sp += __expf(__half2float(swr[(size_t)b * MEM_M + k]) - mrow[row]) / lrow[row];
    }
    u[k] = 0.05f * 0.25f * sp;
    out_eu[k] = eu[k] * 0.99f + sp;
}

// ---------------------------------------------------------------------------
// Fat kernel C: pv_reduce (blocks [0,1024)) || Hebbian update of ev.
// lrow layout: e rows [0,512), s rows [512,1024).
// ---------------------------------------------------------------------------
__global__ __launch_bounds__(256)
void k_pvred_upd(const float* __restrict__ part, const float* __restrict__ lrow,
                 float* __restrict__ R,
                 const float* __restrict__ ev, const float* __restrict__ u,
                 const float* __restrict__ dmean, float* __restrict__ out_ev)
{
    const int tid = threadIdx.x;
    if (blockIdx.x < 1024) {
        const size_t perb4 = (size_t)NROWS * 1024 / 4;
        const size_t i = (size_t)blockIdx.x * 256 + tid;
        const int bank = i >= perb4;
        const size_t off4 = i - (size_t)bank * perb4;
        const int m = (int)(off4 >> 8);
        const float inv = 1.f / lrow[bank * NROWS + m];
        const float4* p = (const float4*)part + (size_t)bank * PV_NC * perb4 + off4;
        float4 s = make_float4(0.f, 0.f, 0.f, 0.f);
        #pragma unroll
        for (int c = 0; c < PV_NC; ++c) {
            const float4 v = p[(size_t)c * perb4];
            s.x += v.x; s.y += v.y; s.z += v.z; s.w += v.w;
        }
        s.x *= inv; s.y *= inv; s.z *= inv; s.w *= inv;
        ((float4*)R)[i] = s;
    } else {
        const int bid = blockIdx.x - 1024;
        const size_t n4 = (size_t)MEM_M * D_HID / 4;
        for (size_t i = (size_t)bid * 256 + tid; i < n4; i += (size_t)1024 * 256) {
            const int k = (int)(i >> 8);
            const int c = (int)(i & 255);
            const float uk = u[k];
            const float om = 1.f - uk;
            const float4 dd = ((const float4*)dmean)[c];
            const float4 b = ((const float4*)ev)[i];
            float4 ob;
            ob.x = b.x * om + dd.x * uk; ob.y = b.y * om + dd.y * uk;
            ob.z = b.z * om + dd.z * uk; ob.w = b.w * om + dd.w * uk;
            ((float4*)out_ev)[i] = ob;
        }
    }
}

// ---------------------------------------------------------------------------
// Fat kernel D: k_ctx (blocks [0,32)) || k_wattn ([32,64)) || update of ek.
// ---------------------------------------------------------------------------
__global__ __launch_bounds__(256)
void k_tail(const float* __restrict__ R,
            const float* __restrict__ Wi_e, const float* __restrict__ bi_e,
            const float* __restrict__ Wi_s, const float* __restrict__ bi_s,
            float* __restrict__ ctx,
            const float* __restrict__ qp, const float* __restrict__ kpw,
            const float* __restrict__ vpw,
            const float* __restrict__ ek, const float* __restrict__ u,
            const float* __restrict__ dmean, float* __restrict__ out_ek)
{
    __shared__ float sm[12384];
    const int tid = threadIdx.x;
    const int bx = blockIdx.x;
    if (bx < 32) {
        const int bank = bx >> 4;
        const int h = bx & 15;
        const float* Rb = R + (size_t)bank * NROWS * D_HID;
        const float* Wv = (bank ? Wi_s : Wi_e) + (size_t)2 * D_HID * D_HID;
        const float* bv = (bank ? bi_s : bi_e) + 2 * D_HID;
        float* cb = ctx + (size_t)bank * BL * D_HID;
        float (*Rs)[129] = (float(*)[129])sm;
        float (*Ws)[129] = (float(*)[129])(sm + 32 * 129);
        const int j = tid & 63;
        const int g = tid >> 6;
        float acc[8];
        #pragma unroll
        for (int i = 0; i < 8; ++i) acc[i] = 0.f;
        for (int ec = 0; ec < D_HID; ec += 128) {
            for (int i = tid; i < 32 * 128; i += 256) {
                const int r = i >> 7, e = i & 127;
                Rs[r][e] = Rb[(size_t)(r * 16 + h) * D_HID + ec + e];
            }
            for (int i = tid; i < 64 * 128; i += 256) {
                const int r = i >> 7, e = i & 127;
                Ws[r][e] = Wv[(size_t)(h * 64 + r) * D_HID + ec + e];
            }
            __syncthreads();
            for (int e = 0; e < 128; ++e) {
                const float w = Ws[j][e];
                #pragma unroll
                for (int i = 0; i < 8; ++i)
                    acc[i] = fmaf(Rs[g + 4 * i][e], w, acc[i]);
            }
            __syncthreads();
        }
        #pragma unroll
        for (int i = 0; i < 8; ++i) {
            const int bl = g + 4 * i;
            cb[(size_t)bl * D_HID + h * 64 + j] = acc[i] + bv[h * 64 + j];
        }
    } else if (bx < 64) {
        const int bl = bx - 32;
        float* q = sm;
        float (*kp)[1024] = (float(*)[1024])(sm + 1024);
        float (*pp)[10] = (float(*)[10])(sm + 1024 + 10240);
        const float* qrow = qp + (size_t)(2 * BL + bl) * D_HID;
        for (int i = tid; i < D_HID; i += 256) q[i] = qrow[i];
        for (int i = tid; i < 10 * D_HID; i += 256) kp[i >> 10][i & 1023] = kpw[i];
        __syncthreads();
        if (tid < 80) {
            const int h = tid / 10, k = tid % 10;
            float s = 0.f;
            for (int jj = 0; jj < 128; ++jj) s += q[h * 128 + jj] * kp[k][h * 128 + jj];
            pp[h][k] = s;
        }
        __syncthreads();
        if (tid < 8) {
            float m = -3.0e38f;
            for (int k = 0; k < 10; ++k) m = fmaxf(m, pp[tid][k]);
            float e[10]; float l = 0.f;
            for (int k = 0; k < 10; ++k) { e[k] = __expf(pp[tid][k] - m); l += e[k]; }
            const float inv = 1.f / l;
            for (int k = 0; k < 10; ++k) pp[tid][k] = e[k] * inv;
        }
        __syncthreads();
        float* cw = ctx + (size_t)(2 * BL + bl) * D_HID;
        for (int f = tid; f < D_HID; f += 256) {
            const int h = f >> 7;
            float s = 0.f;
            #pragma unroll
            for (int k = 0; k < 10; ++k) s += pp[h][k] * vpw[(size_t)k * D_HID + f];
            cw[f] = s;
        }
    } else {
        const int bid = bx - 64;
        const size_t n4 = (size_t)MEM_M * D_HID / 4;
        for (size_t i = (size_t)bid * 256 + tid; i < n4; i += (size_t)1024 * 256) {
            const int k = (int)(i >> 8);
            const int c = (int)(i & 255);
            const float uk = u[k];
            const float om = 1.f - uk;
            const float4 dd = ((const float4*)dmean)[c];
            const float4 a = ((const float4*)ek)[i];
            float4 oa;
            oa.x = a.x * om + dd.x * uk; oa.y = a.y * om + dd.y * uk;
            oa.z = a.z * om + dd.z * uk; oa.w = a.w * om + dd.w * uk;
            ((float4*)out_ek)[i] = oa;
        }
    }
}

// ---------------------------------------------------------------------------
extern "C" void kernel_launch(void* const* d_in, const int* in_sizes, int n_in,
                              void* d_out, int out_size, void* d_ws, size_t ws_size,
                              hipStream_t stream)
{
    (void)in_sizes; (void)n_in; (void)out_size; (void)ws_size;
    const float* q    = (const float*)d_in[0];
    const float* data = (const float*)d_in[1];
    const float* ek   = (const float*)d_in[2];
    const float* ev   = (const float*)d_in[3];
    const float* sk   = (const float*)d_in[4];
    const float* sv   = (const float*)d_in[5];
    const float* wm   = (const float*)d_in[6];
    const float* Wi_e = (const float*)d_in[7];
    const float* bi_e = (const float*)d_in[8];
    const float* Wo_e = (const float*)d_in[9];
    const float* bo_e = (const float*)d_in[10];
    const float* Wi_s = (const float*)d_in[11];
    const float* bi_s = (const float*)d_in[12];
    const float* Wo_s = (const float*)d_in[13];
    const float* bo_s = (const float*)d_in[14];
    const float* Wi_w = (const float*)d_in[15];
    const float* bi_w = (const float*)d_in[16];
    const float* Wo_w = (const float*)d_in[17];
    const float* bo_w = (const float*)d_in[18];
    const float* Wrp  = (const float*)d_in[19];
    const float* brp  = (const float*)d_in[20];
    const float* eu   = (const float*)d_in[21];

    float* out = (float*)d_out;
    float* out_read = out;                       // 32768
    float* out_ek = out + 32768;                 // 20,480,000 floats
    float* out_ev = out_ek + 20480000;           // 20,480,000 floats
    float* out_eu = out_ev + 20480000;           // 20,000

    // ws layout (floats)
    float* ws    = (float*)d_ws;
    float* qp    = ws;                 // 98304
    float* A_e   = qp + 98304;
    float* A_s   = A_e + 655360;
    float* c0_e  = A_s + 524288;       // 640
    float* c0_s  = c0_e + 640;         // 512
    float* dmean = c0_s + 512;         // 1024
    float* u     = dmean + 1024;       // 20480
    float* mrow  = u + 20480;          // 1032
    float* lrow  = mrow + 1032;        // 1032
    float* kpw   = lrow + 1032;        // 10240
    float* vpw   = kpw + 10240;        // 10240
    float* ctx   = vpw + 10240;        // 98304
    float* cat   = ctx + 98304;        // 98304
    float* skpart = cat + 98304;       // 1,310,720 (aliases Rbuf)
    float* Rbuf  = skpart;
    __half* swr  = (__half*)(skpart + 1310720);  // 4*20000 fp16 write-path rows

    ushort* A_e16 = (ushort*)A_e;      // [512][1024] bf16
    ushort* A_s16 = (ushort*)A_s;      // [512][1024] bf16

    // Large scratch in not-yet-final output regions.
    ushort* ekb = (ushort*)out_ek;               // 20000*1024 bf16
    ushort* skb = ekb + (size_t)MEM_M * D_HID;   // 20000*1024 bf16
    float* part = out_ek;                        // 16*512*1024 fp32 (after scores)
    ushort* P_e = (ushort*)out_ev;               // 512*20000 bf16 (exp'd scores)
    ushort* P_s = P_e + (size_t)NROWS * MEM_M;   // 512*20000

    const dim3 b256(256);
    const float sc16 = 0.125f;
    const float sc8  = 0.08838834764831845f;

    // ---- fat head: skinny projections || ek/sk cvt + write-path dots ----
    SkDescs s1;
    s1.d[0] = {q,  Wi_e,            1024, 32};
    s1.d[1] = {q,  Wi_s,            1024, 32};
    s1.d[2] = {q,  Wi_w,            1024, 32};
    s1.d[3] = {wm, Wi_w + 1048576,  1024, 10};
    s1.d[4] = {wm, Wi_w + 2097152,  1024, 10};
    k_head<<<2048, b256, 0, stream>>>(s1, skpart, ek, sk, ekb, data, swr);
    RdDescs r1;
    r1.d[0] = {bi_e,        qp,         32, 1024, sc16};
    r1.d[1] = {bi_s,        qp + 32768, 32, 1024, sc16};
    r1.d[2] = {bi_w,        qp + 65536, 32, 1024, sc8};
    r1.d[3] = {bi_w + 1024, kpw,        10, 1024, 1.f};
    r1.d[4] = {bi_w + 2048, vpw,        10, 1024, 1.f};
    k_skred<<<dim3(32, 5), b256, 0, stream>>>(r1, skpart, 8);

    // T (bf16) + dmean prep + lrow zero
    k_T<<<129, b256, 0, stream>>>(qp, Wi_e, bi_e, Wi_s, bi_s,
                                  A_e16, c0_e, A_s16, c0_s, data, dmean, lrow);

    // merged dual-bank scores with fused exp -> P (bf16), (8,157) grid
    mfma_scores<<<dim3(8, 157), b256, 0, stream>>>(A_e16, ekb, A_s16, skb,
                                                   P_e, P_s, c0_e, c0_s);

    // write-path stats (4 rows) + uk (runs before pv; needs only swr stats)
    k_wstat<<<NBATCH, b256, 0, stream>>>(swr, mrow, lrow);
    k_uk<<<79, b256, 0, stream>>>(swr, mrow, lrow, eu, u, out_eu);

    // PV with fused row-sum -> lrow atomics; XCD chunk-swizzled 512 blocks
    mfma_pv<<<dim3(8, 4, 2 * PV_NC), b256, 0, stream>>>(P_e, P_s, ev, sv,
                                                        part, lrow);

    // pv_reduce || update(ev)  (P dead; lrow complete)
    k_pvred_upd<<<2048, b256, 0, stream>>>(part, lrow, Rbuf, ev, u, dmean, out_ev);

    // ctx || wattn || update(ek)  (part dead)
    k_tail<<<1088, b256, 0, stream>>>(Rbuf, Wi_e, bi_e, Wi_s, bi_s, ctx,
                                      qp, kpw, vpw, ek, u, dmean, out_ek);

    // ---- batched skinny output projections (Rbuf dead from here on) ----
    SkDescs s2;
    s2.d[0] = {ctx,         Wo_e, 1024, 32};
    s2.d[1] = {ctx + 32768, Wo_s, 1024, 32};
    s2.d[2] = {ctx + 65536, Wo_w, 1024, 32};
    s2.d[3] = {ctx,         Wo_e, 1024, 32};   // unused (z<3)
    s2.d[4] = {ctx,         Wo_e, 1024, 32};   // unused
    k_skinny<<<dim3(16, 8, 3), b256, 0, stream>>>(s2, skpart);
    RdDescs r2;
    r2.d[0] = {bo_e, cat,        32, 3072, 1.f};
    r2.d[1] = {bo_s, cat + 1024, 32, 3072, 1.f};
    r2.d[2] = {bo_w, cat + 2048, 32, 3072, 1.f};
    r2.d[3] = r2.d[0];  // unused
    r2.d[4] = r2.d[0];  // unused
    k_skred<<<dim3(32, 3), b256, 0, stream>>>(r2, skpart, 8);

    SkDescs s3;
    s3.d[0] = {cat, Wrp, 3072, 32};
    s3.d[1] = s3.d[0]; s3.d[2] = s3.d[0]; s3.d[3] = s3.d[0]; s3.d[4] = s3.d[0];
    k_skinny<<<dim3(16, 24, 1), b256, 0, stream>>>(s3, skpart);
    RdDescs r3;
    r3.d[0] = {brp, out_read, 32, 1024, 1.f};
    r3.d[1] = r3.d[0]; r3.d[2] = r3.d[0]; r3.d[3] = r3.d[0]; r3.d[4] = r3.d[0];
    k_skred<<<dim3(32, 1), b256, 0, stream>>>(r3, skpart, 24);
}

// Round 19
// 441.065 us; speedup vs baseline: 1.0170x; 1.0170x over previous
//
#include <hip/hip_runtime.h>
#include <hip/hip_fp16.h>
#include <hip/hip_bf16.h>
#include <cstdint>
#include <cstddef>

#define D_HID 1024
#define MEM_M 20000
#define NBATCH 4
#define BL 32
#define NROWS 512
#define BK 32
#define LDT 40    // padded LDS row stride in ushorts (80B, 16B-aligned rows)
#define PV_NC 8   // K-chunks per bank in mfma_pv (part bf16 = 16*1MB = 16.7MB)

typedef __attribute__((ext_vector_type(8))) short short8;
typedef __attribute__((ext_vector_type(4))) float f32x4;
typedef __attribute__((ext_vector_type(16))) float f32x16;
typedef __attribute__((ext_vector_type(4))) unsigned short us4;

__device__ inline ushort f2bf(float f) {
    __hip_bfloat16 b = __float2bfloat16(f);
    return *reinterpret_cast<ushort*>(&b);
}
__device__ inline float h2f(ushort u) {
    __half h; *reinterpret_cast<ushort*>(&h) = u; return __half2float(h);
}
__device__ inline float bf2f(ushort u) {
    unsigned int bits = (unsigned int)u << 16;
    float f; __builtin_memcpy(&f, &bits, 4); return f;
}

// Barrier without the compiler's vmcnt(0) drain (LDS ordering only).
__device__ __forceinline__ void block_sync_lds() {
    asm volatile("s_waitcnt lgkmcnt(0)" ::: "memory");
    __builtin_amdgcn_s_barrier();
}

// ---------------------------------------------------------------------------
// Skinny GEMM (M<=32) split-K partials, shared body.
// ---------------------------------------------------------------------------
struct SkDesc  { const float* A; const float* B; int K; int M; };
struct SkDescs { SkDesc d[5]; };
struct RdDesc  { const float* bias; float* dst; int M; int ldc; float alpha; };
struct RdDescs { RdDesc d[5]; };

__device__ __forceinline__ void skinny_body(const SkDesc dd, float* __restrict__ part,
                                            int gk, int k0, int n0, int tid)
{
    __shared__ float As[32][132];
    __shared__ float Bs[64][129];
    const int K = dd.K, M = dd.M;
    {
        const int r = tid >> 3, cbl = (tid & 7) * 16;
        if (r < M) {
            const float* src = dd.A + (size_t)r * K + k0 + cbl;
            #pragma unroll
            for (int i = 0; i < 4; ++i) {
                const float4 v = *(const float4*)(src + i * 4);
                As[r][cbl + i * 4 + 0] = v.x; As[r][cbl + i * 4 + 1] = v.y;
                As[r][cbl + i * 4 + 2] = v.z; As[r][cbl + i * 4 + 3] = v.w;
            }
        } else {
            #pragma unroll
            for (int i = 0; i < 16; ++i) As[r][cbl + i] = 0.f;
        }
    }
    {
        const int r = tid >> 2, cbl = (tid & 3) * 32;
        const float* src = dd.B + (size_t)(n0 + r) * K + k0 + cbl;
        #pragma unroll
        for (int i = 0; i < 8; ++i) {
            const float4 v = *(const float4*)(src + i * 4);
            Bs[r][cbl + i * 4 + 0] = v.x; Bs[r][cbl + i * 4 + 1] = v.y;
            Bs[r][cbl + i * 4 + 2] = v.z; Bs[r][cbl + i * 4 + 3] = v.w;
        }
    }
    __syncthreads();
    const int n = tid & 63, mg = tid >> 6;
    float acc[8];
    #pragma unroll
    for (int i = 0; i < 8; ++i) acc[i] = 0.f;
    #pragma unroll 4
    for (int k = 0; k < 128; k += 4) {
        const float b0 = Bs[n][k + 0], b1 = Bs[n][k + 1];
        const float b2 = Bs[n][k + 2], b3 = Bs[n][k + 3];
        #pragma unroll
        for (int i = 0; i < 8; ++i) {
            const float4 a = *(const float4*)&As[mg * 8 + i][k];
            acc[i] = fmaf(a.x, b0, fmaf(a.y, b1, fmaf(a.z, b2, fmaf(a.w, b3, acc[i]))));
        }
    }
    #pragma unroll
    for (int i = 0; i < 8; ++i)
        part[((size_t)gk * 32 + mg * 8 + i) * 1024 + n0 + n] = acc[i];
}

__global__ __launch_bounds__(256)
void k_skinny(SkDescs ds, float* __restrict__ part)
{
    skinny_body(ds.d[blockIdx.z], part,
                blockIdx.z * gridDim.y + blockIdx.y,
                blockIdx.y * 128, blockIdx.x * 64, threadIdx.x);
}

// ---------------------------------------------------------------------------
// Fat head: skinny s1 (blocks [0,640)) || row-based cvt ek,sk -> bf16 kvb
// with FUSED write-path dots swr[b][r] = data[b]·ek[r] (fp32) ([640,2048)).
// ---------------------------------------------------------------------------
__global__ __launch_bounds__(256)
void k_head(SkDescs ds, float* __restrict__ part,
            const float* __restrict__ ek, const float* __restrict__ sk,
            ushort* __restrict__ kvb,
            const float* __restrict__ data, __half* __restrict__ swr)
{
    const int bx = blockIdx.x;
    const int tid = threadIdx.x;
    if (bx < 640) {
        const int g = bx >> 7;
        const int rem = bx & 127;
        const int kc = rem >> 4;
        const int n0 = (rem & 15) * 64;
        skinny_body(ds.d[g], part, g * 8 + kc, kc * 128, n0, tid);
    } else {
        const int lane = tid & 63;
        const int wv0 = (bx - 640) * 4 + (tid >> 6);   // wave id in [0,5632)
        const int c16 = lane * 16;
        float dreg[NBATCH][16];
        #pragma unroll
        for (int b = 0; b < NBATCH; ++b)
            #pragma unroll
            for (int j = 0; j < 16; j += 4)
                *(float4*)&dreg[b][j] = *(const float4*)(data + b * D_HID + c16 + j);
        for (int r = wv0; r < 2 * MEM_M; r += 5632) {
            const bool eb = (r < MEM_M);
            const float* src = eb ? (ek + (size_t)r * D_HID + c16)
                                  : (sk + (size_t)(r - MEM_M) * D_HID + c16);
            float v[16];
            #pragma unroll
            for (int j = 0; j < 16; j += 4)
                *(float4*)&v[j] = *(const float4*)(src + j);
            alignas(16) ushort o[16];
            #pragma unroll
            for (int j = 0; j < 16; ++j) o[j] = f2bf(v[j]);
            ushort* dst = kvb + (size_t)r * D_HID + c16;
            *(short8*)dst       = *(const short8*)&o[0];
            *(short8*)(dst + 8) = *(const short8*)&o[8];
            if (eb) {
                float dp[NBATCH];
                #pragma unroll
                for (int b = 0; b < NBATCH; ++b) {
                    float s = 0.f;
                    #pragma unroll
                    for (int j = 0; j < 16; ++j) s = fmaf(dreg[b][j], v[j], s);
                    dp[b] = s;
                }
                #pragma unroll
                for (int b = 0; b < NBATCH; ++b)
                    #pragma unroll
                    for (int off = 32; off > 0; off >>= 1)
                        dp[b] += __shfl_down(dp[b], off);
                if (lane == 0) {
                    #pragma unroll
                    for (int b = 0; b < NBATCH; ++b)
                        swr[(size_t)b * MEM_M + r] = __float2half(dp[b]);
                }
            }
        }
    }
}

__global__ __launch_bounds__(256)
void k_skred(RdDescs ds, const float* __restrict__ part, int nkc)
{
    const int g = blockIdx.y;
    const int m = blockIdx.x;
    const RdDesc dd = ds.d[g];
    if (m >= dd.M) return;
    const int c = threadIdx.x * 4;
    float4 s = make_float4(0.f, 0.f, 0.f, 0.f);
    for (int kc = 0; kc < nkc; ++kc) {
        const float4 v = *(const float4*)&part[((size_t)(g * nkc + kc) * 32 + m) * 1024 + c];
        s.x += v.x; s.y += v.y; s.z += v.z; s.w += v.w;
    }
    const float4 b = *(const float4*)(dd.bias + c);
    float4 o;
    o.x = (s.x + b.x) * dd.alpha; o.y = (s.y + b.y) * dd.alpha;
    o.z = (s.z + b.z) * dd.alpha; o.w = (s.w + b.w) * dd.alpha;
    *(float4*)(dd.dst + (size_t)m * dd.ldc + c) = o;
}

// ---------------------------------------------------------------------------
// MFMA bf16 scores GEMM, both banks 512 rows, (8,157) XCD-chunk swizzle,
// prefetch-2 LDS pipeline, 32x32x16 MFMA. Epilogue writes P = bf16(exp(S+c0)).
// ---------------------------------------------------------------------------
__global__ __launch_bounds__(256)
void mfma_scores(const ushort* __restrict__ A_e, const ushort* __restrict__ ekb,
                 const ushort* __restrict__ A_s, const ushort* __restrict__ skb,
                 ushort* __restrict__ P_e, ushort* __restrict__ P_s,
                 const float* __restrict__ c0_e, const float* __restrict__ c0_s)
{
    __shared__ ushort As[2][128][LDT];
    __shared__ ushort Bs[2][128][LDT];
    const int tid = threadIdx.x;
    // flatten (8,157); chunk = 157 per XCD, bijective
    const int i = blockIdx.x + 8 * blockIdx.y;
    const int xcd = i & 7, idx = i >> 3;
    const int wg = xcd * 157 + idx;
    const int mi = wg & 7, nbk = wg >> 3;
    const int bank = (mi >= 4);
    const int m0 = (bank ? (mi - 4) : mi) * 128;
    const int n0 = nbk * 128;
    const ushort* __restrict__ A = bank ? A_s : A_e;
    const ushort* __restrict__ B = bank ? skb : ekb;
    ushort* __restrict__ P = bank ? P_s : P_e;
    const float* __restrict__ c0 = bank ? c0_s : c0_e;

    const int wid = tid >> 6, lane = tid & 63;
    const int wr = (wid >> 1) * 64, wc = (wid & 1) * 64;
    const int l31 = lane & 31, l2 = lane >> 5;

    const int srow = tid >> 1;
    const int ac = (tid & 1) * 16;
    int gbrow = n0 + srow; if (gbrow > MEM_M - 1) gbrow = MEM_M - 1;
    const ushort* Ap = A + (size_t)(m0 + srow) * 1024 + ac;
    const ushort* Bp = B + (size_t)gbrow * 1024 + ac;

    f32x16 acc[2][2];
    #pragma unroll
    for (int fm = 0; fm < 2; ++fm)
        #pragma unroll
        for (int fn = 0; fn < 2; ++fn)
            #pragma unroll
            for (int r = 0; r < 16; ++r) acc[fm][fn][r] = 0.f;

    auto MF = [&](int bu) {
        short8 a[2][2], b[2][2];
        #pragma unroll
        for (int f = 0; f < 2; ++f)
            #pragma unroll
            for (int kh = 0; kh < 2; ++kh) {
                a[f][kh] = *(const short8*)&As[bu][wr + f * 32 + l31][kh * 16 + l2 * 8];
                b[f][kh] = *(const short8*)&Bs[bu][wc + f * 32 + l31][kh * 16 + l2 * 8];
            }
        #pragma unroll
        for (int fm = 0; fm < 2; ++fm)
            #pragma unroll
            for (int fn = 0; fn < 2; ++fn)
                #pragma unroll
                for (int kh = 0; kh < 2; ++kh)
                    acc[fm][fn] = __builtin_amdgcn_mfma_f32_32x32x16_bf16(
                        a[fm][kh], b[fn][kh], acc[fm][fn], 0, 0, 0);
    };

    short8 a00, a01, b00, b01;   // prefetch set 0 (even tiles)
    short8 a10, a11, b10, b11;   // prefetch set 1 (odd tiles)

#define SC_LOAD0(KT) { a00 = *(const short8*)(Ap + (KT)); a01 = *(const short8*)(Ap + (KT) + 8); \
                       b00 = *(const short8*)(Bp + (KT)); b01 = *(const short8*)(Bp + (KT) + 8); }
#define SC_LOAD1(KT) { a10 = *(const short8*)(Ap + (KT)); a11 = *(const short8*)(Ap + (KT) + 8); \
                       b10 = *(const short8*)(Bp + (KT)); b11 = *(const short8*)(Bp + (KT) + 8); }
#define SC_STORE0(BU) { *(short8*)&As[BU][srow][ac] = a00; *(short8*)&As[BU][srow][ac + 8] = a01; \
                        *(short8*)&Bs[BU][srow][ac] = b00; *(short8*)&Bs[BU][srow][ac + 8] = b01; }
#define SC_STORE1(BU) { *(short8*)&As[BU][srow][ac] = a10; *(short8*)&As[BU][srow][ac + 8] = a11; \
                        *(short8*)&Bs[BU][srow][ac] = b10; *(short8*)&Bs[BU][srow][ac + 8] = b11; }

    SC_LOAD0(0);
    SC_LOAD1(32);
    SC_STORE0(0);
    block_sync_lds();
    for (int it = 0; it < 16; ++it) {
        const int kt = it * 64;
        if (it < 15) SC_LOAD0(kt + 64);
        MF(0);
        SC_STORE1(1);
        block_sync_lds();
        if (it < 15) SC_LOAD1(kt + 96);
        MF(1);
        if (it < 15) SC_STORE0(0);
        block_sync_lds();
    }
#undef SC_LOAD0
#undef SC_LOAD1
#undef SC_STORE0
#undef SC_STORE1

    #pragma unroll
    for (int fm = 0; fm < 2; ++fm) {
        #pragma unroll
        for (int fn = 0; fn < 2; ++fn) {
            #pragma unroll
            for (int r = 0; r < 16; ++r) {
                const int row = m0 + wr + fm * 32 + (r & 3) + 8 * (r >> 2) + 4 * l2;
                const int col = n0 + wc + fn * 32 + l31;
                if (col < MEM_M)
                    P[(size_t)row * MEM_M + col] = f2bf(__expf(acc[fm][fn][r] + c0[row]));
            }
        }
    }
}

// ---------------------------------------------------------------------------
// MFMA bf16 PV GEMM with FUSED row-sum of P (nI==0 blocks; lrow atomics;
// lrow pre-zeroed by k_T). part stored as bf16 (partial sums ~1e2 vs
// R ~1e-2: bf16 rel-err 2^-9 contributes ~4e-5 to R — negligible; validated
// by r17's output-0 pass).
// ---------------------------------------------------------------------------
__global__ __launch_bounds__(256)
void mfma_pv(const ushort* __restrict__ P_e, const ushort* __restrict__ P_s,
             const float* __restrict__ ev, const float* __restrict__ sv,
             ushort* __restrict__ part, float* __restrict__ lrow)
{
    __shared__ ushort As[2][128][LDT];
    __shared__ ushort Bs[2][128][LDT];
    const int tid = threadIdx.x;
    // chunked XCD swizzle (n fastest, then m, then z)
    const int bid = blockIdx.x + 8 * (blockIdx.y + 4 * blockIdx.z);
    const int wgs = (bid & 7) * 64 + (bid >> 3);
    const int nI = wgs & 7, mI = (wgs >> 3) & 3;
    const int z = wgs >> 5;                 // [0,16)
    const int bank = z >> 3, c = z & 7;
    const ushort* __restrict__ P = bank ? P_s : P_e;
    const float* __restrict__ V = bank ? sv : ev;
    const int m0 = mI * 128, n0 = nI * 128;
    const int ks0 = (c * 625) / PV_NC, ks1 = ((c + 1) * 625) / PV_NC;
    const int wid = tid >> 6, lane = tid & 63;
    const int wr = (wid >> 1) * 64, wc = (wid & 1) * 64;
    const int l31 = lane & 31, l2 = lane >> 5;
    const int kb = (tid & 7) * 4, nb2 = (tid >> 3) * 4;
    const int srow = tid >> 1, ac = (tid & 1) * 16;
    const ushort* Pp = P + (size_t)(m0 + srow) * MEM_M + ac;
    const bool doSum = (nI == 0) && !(wid & 1);   // wave-uniform
    float rsum0 = 0.f, rsum1 = 0.f;               // rows wr+l31, wr+32+l31

    f32x16 acc[2][2];
    #pragma unroll
    for (int fm = 0; fm < 2; ++fm)
        #pragma unroll
        for (int fn = 0; fn < 2; ++fn)
            #pragma unroll
            for (int r = 0; r < 16; ++r) acc[fm][fn][r] = 0.f;

    auto MF = [&](int bu) {
        short8 a[2][2], b[2][2];
        #pragma unroll
        for (int f = 0; f < 2; ++f)
            #pragma unroll
            for (int kh = 0; kh < 2; ++kh) {
                a[f][kh] = *(const short8*)&As[bu][wr + f * 32 + l31][kh * 16 + l2 * 8];
                b[f][kh] = *(const short8*)&Bs[bu][wc + f * 32 + l31][kh * 16 + l2 * 8];
            }
        if (doSum) {
            #pragma unroll
            for (int kh = 0; kh < 2; ++kh)
                #pragma unroll
                for (int j = 0; j < 8; ++j) {
                    rsum0 += bf2f((ushort)a[0][kh][j]);
                    rsum1 += bf2f((ushort)a[1][kh][j]);
                }
        }
        #pragma unroll
        for (int fm = 0; fm < 2; ++fm)
            #pragma unroll
            for (int fn = 0; fn < 2; ++fn)
                #pragma unroll
                for (int kh = 0; kh < 2; ++kh)
                    acc[fm][fn] = __builtin_amdgcn_mfma_f32_32x32x16_bf16(
                        a[fm][kh], b[fn][kh], acc[fm][fn], 0, 0, 0);
    };

    short8 pa00, pa01, pa10, pa11;
    float4 q00, q01, q02, q03, q10, q11, q12, q13;

#define PV_LOAD0(T) { const int kt = (T) * 32; \
    pa00 = *(const short8*)(Pp + kt); pa01 = *(const short8*)(Pp + kt + 8); \
    q00 = *(const float4*)(V + (size_t)(kt + kb + 0) * 1024 + n0 + nb2); \
    q01 = *(const float4*)(V + (size_t)(kt + kb + 1) * 1024 + n0 + nb2); \
    q02 = *(const float4*)(V + (size_t)(kt + kb + 2) * 1024 + n0 + nb2); \
    q03 = *(const float4*)(V + (size_t)(kt + kb + 3) * 1024 + n0 + nb2); }
#define PV_LOAD1(T) { const int kt = (T) * 32; \
    pa10 = *(const short8*)(Pp + kt); pa11 = *(const short8*)(Pp + kt + 8); \
    q10 = *(const float4*)(V + (size_t)(kt + kb + 0) * 1024 + n0 + nb2); \
    q11 = *(const float4*)(V + (size_t)(kt + kb + 1) * 1024 + n0 + nb2); \
    q12 = *(const float4*)(V + (size_t)(kt + kb + 2) * 1024 + n0 + nb2); \
    q13 = *(const float4*)(V + (size_t)(kt + kb + 3) * 1024 + n0 + nb2); }
#define PV_STORE0(BU) { \
    *(short8*)&As[BU][srow][ac] = pa00; *(short8*)&As[BU][srow][ac + 8] = pa01; \
    us4 w; \
    w.x = f2bf(q00.x); w.y = f2bf(q01.x); w.z = f2bf(q02.x); w.w = f2bf(q03.x); \
    *(us4*)&Bs[BU][nb2 + 0][kb] = w; \
    w.x = f2bf(q00.y); w.y = f2bf(q01.y); w.z = f2bf(q02.y); w.w = f2bf(q03.y); \
    *(us4*)&Bs[BU][nb2 + 1][kb] = w; \
    w.x = f2bf(q00.z); w.y = f2bf(q01.z); w.z = f2bf(q02.z); w.w = f2bf(q03.z); \
    *(us4*)&Bs[BU][nb2 + 2][kb] = w; \
    w.x = f2bf(q00.w); w.y = f2bf(q01.w); w.z = f2bf(q02.w); w.w = f2bf(q03.w); \
    *(us4*)&Bs[BU][nb2 + 3][kb] = w; }
#define PV_STORE1(BU) { \
    *(short8*)&As[BU][srow][ac] = pa10; *(short8*)&As[BU][srow][ac + 8] = pa11; \
    us4 w; \
    w.x = f2bf(q10.x); w.y = f2bf(q11.x); w.z = f2bf(q12.x); w.w = f2bf(q13.x); \
    *(us4*)&Bs[BU][nb2 + 0][kb] = w; \
    w.x = f2bf(q10.y); w.y = f2bf(q11.y); w.z = f2bf(q12.y); w.w = f2bf(q13.y); \
    *(us4*)&Bs[BU][nb2 + 1][kb] = w; \
    w.x = f2bf(q10.z); w.y = f2bf(q11.z); w.z = f2bf(q12.z); w.w = f2bf(q13.z); \
    *(us4*)&Bs[BU][nb2 + 2][kb] = w; \
    w.x = f2bf(q10.w); w.y = f2bf(q11.w); w.z = f2bf(q12.w); w.w = f2bf(q13.w); \
    *(us4*)&Bs[BU][nb2 + 3][kb] = w; }

    PV_LOAD0(ks0);
    if (ks0 + 1 < ks1) PV_LOAD1(ks0 + 1);
    PV_STORE0(0);
    block_sync_lds();
    for (int t = ks0; t < ks1; t += 2) {
        if (t + 2 < ks1) PV_LOAD0(t + 2);
        MF(0);
        if (t + 1 < ks1) PV_STORE1(1);
        block_sync_lds();
        if (t + 1 < ks1) {
            if (t + 3 < ks1) PV_LOAD1(t + 3);
            MF(1);
            if (t + 2 < ks1) PV_STORE0(0);
            block_sync_lds();
        }
    }
#undef PV_LOAD0
#undef PV_LOAD1
#undef PV_STORE0
#undef PV_STORE1

    if (nI == 0 && !(wid & 1)) {
        rsum0 += __shfl_down(rsum0, 32);
        rsum1 += __shfl_down(rsum1, 32);
        if (lane < 32) {
            atomicAdd(&lrow[bank * NROWS + m0 + wr + lane], rsum0);
            atomicAdd(&lrow[bank * NROWS + m0 + wr + 32 + lane], rsum1);
        }
    }

    ushort* __restrict__ po = part + (size_t)z * NROWS * 1024;
    #pragma unroll
    for (int fm = 0; fm < 2; ++fm)
        #pragma unroll
        for (int fn = 0; fn < 2; ++fn)
            #pragma unroll
            for (int r = 0; r < 16; ++r) {
                const int row = m0 + wr + fm * 32 + (r & 3) + 8 * (r >> 2) + 4 * l2;
                const int col = n0 + wc + fn * 32 + l31;
                po[(size_t)row * 1024 + col] = f2bf(acc[fm][fn][r]);
            }
}

// ---------------------------------------------------------------------------
// T rows (folded K-projection), bf16 output; fused dmean prep + lrow zero.
// ---------------------------------------------------------------------------
__global__ __launch_bounds__(256)
void k_T(const float* __restrict__ qp,
         const float* __restrict__ Wi_e, const float* __restrict__ bi_e,
         const float* __restrict__ Wi_s, const float* __restrict__ bi_s,
         ushort* __restrict__ A_e, float* __restrict__ c0_e,
         ushort* __restrict__ A_s, float* __restrict__ c0_s,
         const float* __restrict__ data, float* __restrict__ dmean,
         float* __restrict__ lrow)
{
    const int bq = blockIdx.x;
    const int tid = threadIdx.x;
    if (bq >= 128) {
        for (int t = tid; t < D_HID; t += 256) {
            float s = 0.f;
            #pragma unroll
            for (int b = 0; b < NBATCH; ++b) s += data[b * D_HID + t];
            dmean[t] = 0.25f * s;
        }
        for (int t = tid; t < 2 * NROWS; t += 256) lrow[t] = 0.f;
        return;
    }
    const int bank = bq >> 6;
    const int h = (bq >> 2) & 15;
    const int q4 = bq & 3;
    const float* qpB = qp + (size_t)bank * BL * D_HID;
    const float* Wk = (bank ? Wi_s : Wi_e) + (size_t)D_HID * D_HID;
    const float* bk = (bank ? bi_s : bi_e) + D_HID;
    ushort* T  = bank ? A_s : A_e;
    float* c0 = bank ? c0_s : c0_e;

    __shared__ float qs[32][64];
    for (int i = tid; i < 32 * 64; i += 256) {
        const int r = i >> 6, j = i & 63;
        qs[r][j] = qpB[(size_t)r * D_HID + h * 64 + j];
    }
    __syncthreads();
    const int e = q4 * 256 + tid;
    float acc[32];
    #pragma unroll
    for (int r = 0; r < 32; ++r) acc[r] = 0.f;
    for (int j = 0; j < 64; ++j) {
        const float w = Wk[(size_t)(h * 64 + j) * D_HID + e];
        #pragma unroll
        for (int r = 0; r < 32; ++r) acc[r] = fmaf(qs[r][j], w, acc[r]);
    }
    #pragma unroll
    for (int r = 0; r < 32; ++r) T[(size_t)(r * 16 + h) * 1024 + e] = f2bf(acc[r]);
    if (q4 == 0 && tid < 32) {
        float s = 0.f;
        for (int j = 0; j < 64; ++j) s += qs[tid][j] * bk[h * 64 + j];
        c0[tid * 16 + h] = s;
    }
}

// ---------------------------------------------------------------------------
// Stats (m,l) for the 4 write-path rows only (large-magnitude scores in swr).
// ---------------------------------------------------------------------------
__global__ __launch_bounds__(256)
void k_wstat(const __half* __restrict__ swr,
             float* __restrict__ mrow, float* __restrict__ lrow)
{
    const int b = blockIdx.x;                 // 0..3
    const ushort* p = (const ushort*)swr + (size_t)b * MEM_M;
    __shared__ float red_m[256];
    __shared__ float red_l[256];
    const int tid = threadIdx.x;
    float m = -3.0e38f, l = 0.f;
    for (int c = tid; c < MEM_M / 8; c += 256) {
        alignas(16) ushort t[8];
        *(short8*)t = *(const short8*)(p + c * 8);
        float v[8];
        #pragma unroll
        for (int j = 0; j < 8; ++j) v[j] = h2f(t[j]);
        float cm = v[0];
        #pragma unroll
        for (int j = 1; j < 8; ++j) cm = fmaxf(cm, v[j]);
        const float nm = fmaxf(m, cm);
        float s = 0.f;
        #pragma unroll
        for (int j = 0; j < 8; ++j) s += __expf(v[j] - nm);
        l = l * __expf(m - nm) + s;
        m = nm;
    }
    red_m[tid] = m; red_l[tid] = l; __syncthreads();
    for (int s = 128; s > 0; s >>= 1) {
        if (tid < s) {
            const float m2 = fmaxf(red_m[tid], red_m[tid + s]);
            red_l[tid] = red_l[tid] * __expf(red_m[tid] - m2)
                       + red_l[tid + s] * __expf(red_m[tid + s] - m2);
            red_m[tid] = m2;
        }
        __syncthreads();
    }
    if (tid == 0) { mrow[2 * NROWS + b] = red_m[0]; lrow[2 * NROWS + b] = red_l[0]; }
}

// u[k] and new_eu[k] from the 4 write-path fp16 rows in swr.
__global__ __launch_bounds__(256)
void k_uk(const __half* __restrict__ swr,
          const float* __restrict__ mrow, const float* __restrict__ lrow,
          const float* __restrict__ eu,
          float* __restrict__ u, float* __restrict__ out_eu)
{
    const int k = blockIdx.x * 256 + threadIdx.x;
    if (k >= MEM_M) return;
    float sp = 0.f;
    #pragma unroll
    for (int b = 0; b < NBATCH; ++b) {
        const int row = 2 * NROWS + b;
        sp += __expf(__half2float(swr[(size_t)b * MEM_M + k]) - mrow[row]) / lrow[row];
    }
    u[k] = 0.05f * 0.25f * sp;
    out_eu[k] = eu[k] * 0.99f + sp;
}

// ---------------------------------------------------------------------------
// Fat kernel C: pv_reduce bf16 parts (blocks [0,512)) || update of ev
// ([512,1536)). lrow layout: e rows [0,512), s rows [512,1024).
// ---------------------------------------------------------------------------
__global__ __launch_bounds__(256)
void k_pvred_upd(const ushort* __restrict__ part, const float* __restrict__ lrow,
                 float* __restrict__ R,
                 const float* __restrict__ ev, const float* __restrict__ u,
                 const float* __restrict__ dmean, float* __restrict__ out_ev)
{
    const int tid = threadIdx.x;
    if (blockIdx.x < 512) {
        // groups of 8 elements; 65536 groups per bank
        const size_t i = (size_t)blockIdx.x * 256 + tid;    // [0, 131072)
        const int bank = i >= 65536;
        const size_t g = i - (size_t)bank * 65536;
        const int m = (int)(g >> 7);                        // 128 groups per row
        const float inv = 1.f / lrow[bank * NROWS + m];
        const ushort* p = part + (size_t)bank * PV_NC * (NROWS * 1024) + g * 8;
        float s[8];
        #pragma unroll
        for (int j = 0; j < 8; ++j) s[j] = 0.f;
        #pragma unroll
        for (int c = 0; c < PV_NC; ++c) {
            alignas(16) ushort t[8];
            *(short8*)t = *(const short8*)(p + (size_t)c * (NROWS * 1024));
            #pragma unroll
            for (int j = 0; j < 8; ++j) s[j] += bf2f(t[j]);
        }
        float* dst = R + (size_t)bank * NROWS * 1024 + g * 8;
        float4 o0, o1;
        o0.x = s[0] * inv; o0.y = s[1] * inv; o0.z = s[2] * inv; o0.w = s[3] * inv;
        o1.x = s[4] * inv; o1.y = s[5] * inv; o1.z = s[6] * inv; o1.w = s[7] * inv;
        *(float4*)dst = o0;
        *(float4*)(dst + 4) = o1;
    } else {
        const int bid = blockIdx.x - 512;
        const size_t n4 = (size_t)MEM_M * D_HID / 4;
        for (size_t i = (size_t)bid * 256 + tid; i < n4; i += (size_t)1024 * 256) {
            const int k = (int)(i >> 8);
            const int c = (int)(i & 255);
            const float uk = u[k];
            const float om = 1.f - uk;
            const float4 dd = ((const float4*)dmean)[c];
            const float4 b = ((const float4*)ev)[i];
            float4 ob;
            ob.x = b.x * om + dd.x * uk; ob.y = b.y * om + dd.y * uk;
            ob.z = b.z * om + dd.z * uk; ob.w = b.w * om + dd.w * uk;
            ((float4*)out_ev)[i] = ob;
        }
    }
}

// ---------------------------------------------------------------------------
// Fat kernel D: k_ctx (blocks [0,32)) || k_wattn ([32,64)) || update of ek.
// ---------------------------------------------------------------------------
__global__ __launch_bounds__(256)
void k_tail(const float* __restrict__ R,
            const float* __restrict__ Wi_e, const float* __restrict__ bi_e,
            const float* __restrict__ Wi_s, const float* __restrict__ bi_s,
            float* __restrict__ ctx,
            const float* __restrict__ qp, const float* __restrict__ kpw,
            const float* __restrict__ vpw,
            const float* __restrict__ ek, const float* __restrict__ u,
            const float* __restrict__ dmean, float* __restrict__ out_ek)
{
    __shared__ float sm[12384];
    const int tid = threadIdx.x;
    const int bx = blockIdx.x;
    if (bx < 32) {
        const int bank = bx >> 4;
        const int h = bx & 15;
        const float* Rb = R + (size_t)bank * NROWS * D_HID;
        const float* Wv = (bank ? Wi_s : Wi_e) + (size_t)2 * D_HID * D_HID;
        const float* bv = (bank ? bi_s : bi_e) + 2 * D_HID;
        float* cb = ctx + (size_t)bank * BL * D_HID;
        float (*Rs)[129] = (float(*)[129])sm;
        float (*Ws)[129] = (float(*)[129])(sm + 32 * 129);
        const int j = tid & 63;
        const int g = tid >> 6;
        float acc[8];
        #pragma unroll
        for (int i = 0; i < 8; ++i) acc[i] = 0.f;
        for (int ec = 0; ec < D_HID; ec += 128) {
            for (int i = tid; i < 32 * 128; i += 256) {
                const int r = i >> 7, e = i & 127;
                Rs[r][e] = Rb[(size_t)(r * 16 + h) * D_HID + ec + e];
            }
            for (int i = tid; i < 64 * 128; i += 256) {
                const int r = i >> 7, e = i & 127;
                Ws[r][e] = Wv[(size_t)(h * 64 + r) * D_HID + ec + e];
            }
            __syncthreads();
            for (int e = 0; e < 128; ++e) {
                const float w = Ws[j][e];
                #pragma unroll
                for (int i = 0; i < 8; ++i)
                    acc[i] = fmaf(Rs[g + 4 * i][e], w, acc[i]);
            }
            __syncthreads();
        }
        #pragma unroll
        for (int i = 0; i < 8; ++i) {
            const int bl = g + 4 * i;
            cb[(size_t)bl * D_HID + h * 64 + j] = acc[i] + bv[h * 64 + j];
        }
    } else if (bx < 64) {
        const int bl = bx - 32;
        float* q = sm;
        float (*kp)[1024] = (float(*)[1024])(sm + 1024);
        float (*pp)[10] = (float(*)[10])(sm + 1024 + 10240);
        const float* qrow = qp + (size_t)(2 * BL + bl) * D_HID;
        for (int i = tid; i < D_HID; i += 256) q[i] = qrow[i];
        for (int i = tid; i < 10 * D_HID; i += 256) kp[i >> 10][i & 1023] = kpw[i];
        __syncthreads();
        if (tid < 80) {
            const int h = tid / 10, k = tid % 10;
            float s = 0.f;
            for (int jj = 0; jj < 128; ++jj) s += q[h * 128 + jj] * kp[k][h * 128 + jj];
            pp[h][k] = s;
        }
        __syncthreads();
        if (tid < 8) {
            float m = -3.0e38f;
            for (int k = 0; k < 10; ++k) m = fmaxf(m, pp[tid][k]);
            float e[10]; float l = 0.f;
            for (int k = 0; k < 10; ++k) { e[k] = __expf(pp[tid][k] - m); l += e[k]; }
            const float inv = 1.f / l;
            for (int k = 0; k < 10; ++k) pp[tid][k] = e[k] * inv;
        }
        __syncthreads();
        float* cw = ctx + (size_t)(2 * BL + bl) * D_HID;
        for (int f = tid; f < D_HID; f += 256) {
            const int h = f >> 7;
            float s = 0.f;
            #pragma unroll
            for (int k = 0; k < 10; ++k) s += pp[h][k] * vpw[(size_t)k * D_HID + f];
            cw[f] = s;
        }
    } else {
        const int bid = bx - 64;
        const size_t n4 = (size_t)MEM_M * D_HID / 4;
        for (size_t i = (size_t)bid * 256 + tid; i < n4; i += (size_t)1024 * 256) {
            const int k = (int)(i >> 8);
            const int c = (int)(i & 255);
            const float uk = u[k];
            const float om = 1.f - uk;
            const float4 dd = ((const float4*)dmean)[c];
            const float4 a = ((const float4*)ek)[i];
            float4 oa;
            oa.x = a.x * om + dd.x * uk; oa.y = a.y * om + dd.y * uk;
            oa.z = a.z * om + dd.z * uk; oa.w = a.w * om + dd.w * uk;
            ((float4*)out_ek)[i] = oa;
        }
    }
}

// ---------------------------------------------------------------------------
extern "C" void kernel_launch(void* const* d_in, const int* in_sizes, int n_in,
                              void* d_out, int out_size, void* d_ws, size_t ws_size,
                              hipStream_t stream)
{
    (void)in_sizes; (void)n_in; (void)out_size; (void)ws_size;
    const float* q    = (const float*)d_in[0];
    const float* data = (const float*)d_in[1];
    const float* ek   = (const float*)d_in[2];
    const float* ev   = (const float*)d_in[3];
    const float* sk   = (const float*)d_in[4];
    const float* sv   = (const float*)d_in[5];
    const float* wm   = (const float*)d_in[6];
    const float* Wi_e = (const float*)d_in[7];
    const float* bi_e = (const float*)d_in[8];
    const float* Wo_e = (const float*)d_in[9];
    const float* bo_e = (const float*)d_in[10];
    const float* Wi_s = (const float*)d_in[11];
    const float* bi_s = (const float*)d_in[12];
    const float* Wo_s = (const float*)d_in[13];
    const float* bo_s = (const float*)d_in[14];
    const float* Wi_w = (const float*)d_in[15];
    const float* bi_w = (const float*)d_in[16];
    const float* Wo_w = (const float*)d_in[17];
    const float* bo_w = (const float*)d_in[18];
    const float* Wrp  = (const float*)d_in[19];
    const float* brp  = (const float*)d_in[20];
    const float* eu   = (const float*)d_in[21];

    float* out = (float*)d_out;
    float* out_read = out;                       // 32768
    float* out_ek = out + 32768;                 // 20,480,000 floats
    float* out_ev = out_ek + 20480000;           // 20,480,000 floats
    float* out_eu = out_ev + 20480000;           // 20,000

    // ws layout (floats)
    float* ws    = (float*)d_ws;
    float* qp    = ws;                 // 98304
    float* A_e   = qp + 98304;
    float* A_s   = A_e + 655360;
    float* c0_e  = A_s + 524288;       // 640
    float* c0_s  = c0_e + 640;         // 512
    float* dmean = c0_s + 512;         // 1024
    float* u     = dmean + 1024;       // 20480
    float* mrow  = u + 20480;          // 1032
    float* lrow  = mrow + 1032;        // 1032
    float* kpw   = lrow + 1032;        // 10240
    float* vpw   = kpw + 10240;        // 10240
    float* ctx   = vpw + 10240;        // 98304
    float* cat   = ctx + 98304;        // 98304
    float* skpart = cat + 98304;       // 1,310,720 (aliases Rbuf)
    float* Rbuf  = skpart;
    __half* swr  = (__half*)(skpart + 1310720);  // 4*20000 fp16 write-path rows

    ushort* A_e16 = (ushort*)A_e;      // [512][1024] bf16
    ushort* A_s16 = (ushort*)A_s;      // [512][1024] bf16

    // Large scratch in not-yet-final output regions.
    ushort* ekb = (ushort*)out_ek;               // 20000*1024 bf16
    ushort* skb = ekb + (size_t)MEM_M * D_HID;   // 20000*1024 bf16
    ushort* part16 = (ushort*)out_ek;            // 16*512*1024 bf16 (after scores)
    ushort* P_e = (ushort*)out_ev;               // 512*20000 bf16 (exp'd scores)
    ushort* P_s = P_e + (size_t)NROWS * MEM_M;   // 512*20000

    const dim3 b256(256);
    const float sc16 = 0.125f;
    const float sc8  = 0.08838834764831845f;

    // ---- fat head: skinny projections || ek/sk cvt + write-path dots ----
    SkDescs s1;
    s1.d[0] = {q,  Wi_e,            1024, 32};
    s1.d[1] = {q,  Wi_s,            1024, 32};
    s1.d[2] = {q,  Wi_w,            1024, 32};
    s1.d[3] = {wm, Wi_w + 1048576,  1024, 10};
    s1.d[4] = {wm, Wi_w + 2097152,  1024, 10};
    k_head<<<2048, b256, 0, stream>>>(s1, skpart, ek, sk, ekb, data, swr);
    RdDescs r1;
    r1.d[0] = {bi_e,        qp,         32, 1024, sc16};
    r1.d[1] = {bi_s,        qp + 32768, 32, 1024, sc16};
    r1.d[2] = {bi_w,        qp + 65536, 32, 1024, sc8};
    r1.d[3] = {bi_w + 1024, kpw,        10, 1024, 1.f};
    r1.d[4] = {bi_w + 2048, vpw,        10, 1024, 1.f};
    k_skred<<<dim3(32, 5), b256, 0, stream>>>(r1, skpart, 8);

    // T (bf16) + dmean prep + lrow zero
    k_T<<<129, b256, 0, stream>>>(qp, Wi_e, bi_e, Wi_s, bi_s,
                                  A_e16, c0_e, A_s16, c0_s, data, dmean, lrow);

    // merged dual-bank scores with fused exp -> P (bf16), (8,157) grid
    mfma_scores<<<dim3(8, 157), b256, 0, stream>>>(A_e16, ekb, A_s16, skb,
                                                   P_e, P_s, c0_e, c0_s);

    // write-path stats (4 rows) + uk (separate launches; r16-proven ordering)
    k_wstat<<<NBATCH, b256, 0, stream>>>(swr, mrow, lrow);
    k_uk<<<79, b256, 0, stream>>>(swr, mrow, lrow, eu, u, out_eu);

    // PV with fused row-sum -> lrow atomics; bf16 part; XCD swizzled
    mfma_pv<<<dim3(8, 4, 2 * PV_NC), b256, 0, stream>>>(P_e, P_s, ev, sv,
                                                        part16, lrow);

    // pv_reduce (bf16 parts, 512 blocks) || update(ev)  (P dead; lrow done)
    k_pvred_upd<<<1536, b256, 0, stream>>>(part16, lrow, Rbuf, ev, u, dmean, out_ev);

    // ctx || wattn || update(ek)  (part dead)
    k_tail<<<1088, b256, 0, stream>>>(Rbuf, Wi_e, bi_e, Wi_s, bi_s, ctx,
                                      qp, kpw, vpw, ek, u, dmean, out_ek);

    // ---- batched skinny output projections (Rbuf dead from here on) ----
    SkDescs s2;
    s2.d[0] = {ctx,         Wo_e, 1024, 32};
    s2.d[1] = {ctx + 32768, Wo_s, 1024, 32};
    s2.d[2] = {ctx + 65536, Wo_w, 1024, 32};
    s2.d[3] = {ctx,         Wo_e, 1024, 32};   // unused (z<3)
    s2.d[4] = {ctx,         Wo_e, 1024, 32};   // unused
    k_skinny<<<dim3(16, 8, 3), b256, 0, stream>>>(s2, skpart);
    RdDescs r2;
    r2.d[0] = {bo_e, cat,        32, 3072, 1.f};
    r2.d[1] = {bo_s, cat + 1024, 32, 3072, 1.f};
    r2.d[2] = {bo_w, cat + 2048, 32, 3072, 1.f};
    r2.d[3] = r2.d[0];  // unused
    r2.d[4] = r2.d[0];  // unused
    k_skred<<<dim3(32, 3), b256, 0, stream>>>(r2, skpart, 8);

    SkDescs s3;
    s3.d[0] = {cat, Wrp, 3072, 32};
    s3.d[1] = s3.d[0]; s3.d[2] = s3.d[0]; s3.d[3] = s3.d[0]; s3.d[4] = s3.d[0];
    k_skinny<<<dim3(16, 24, 1), b256, 0, stream>>>(s3, skpart);
    RdDescs r3;
    r3.d[0] = {brp, out_read, 32, 1024, 1.f};
    r3.d[1] = r3.d[0]; r3.d[2] = r3.d[0]; r3.d[3] = r3.d[0]; r3.d[4] = r3.d[0];
    k_skred<<<dim3(32, 1), b256, 0, stream>>>(r3, skpart, 24);
}